// Round 10
// baseline (601.593 us; speedup 1.0000x reference)
//
#include <hip/hip_runtime.h>
#include <math.h>

#define B_   64
#define T_   500
#define IN_  1024
#define G_   8
#define HG_  128
#define J3_  384   // 3*HG

typedef _Float16 half8 __attribute__((ext_vector_type(8)));
typedef _Float16 half4 __attribute__((ext_vector_type(4)));
typedef float    f32x4 __attribute__((ext_vector_type(4)));

// sigmoid(a) = rcp(1 + exp2(-log2e * a)); tanh(p) = 2*rcp(1+exp2(-2log2e*p))-1.
// The scale constants are folded into the f16 weights + bias seeds.
#define S_RZ (-1.44269504f)
#define S_N  (-2.88539008f)

static __device__ __forceinline__ half8 cvt_half8_s(const float* p, float s) {
    const float4 a = *(const float4*)p;
    const float4 b = *(const float4*)(p + 4);
    half8 h;
    h[0]=(_Float16)(a.x*s); h[1]=(_Float16)(a.y*s); h[2]=(_Float16)(a.z*s); h[3]=(_Float16)(a.w*s);
    h[4]=(_Float16)(b.x*s); h[5]=(_Float16)(b.y*s); h[6]=(_Float16)(b.z*s); h[7]=(_Float16)(b.w*s);
    return h;
}

// opaque reg-to-reg barrier: prevents rematerialization of loop-invariant state
static __device__ __forceinline__ void pin_frag(half8& h) {
    f32x4 t = __builtin_bit_cast(f32x4, h);
    float a = t[0], b = t[1], c = t[2], d = t[3];
    asm volatile("" : "+v"(a), "+v"(b), "+v"(c), "+v"(d));
    t[0] = a; t[1] = b; t[2] = c; t[3] = d;
    h = __builtin_bit_cast(half8, t);
}
static __device__ __forceinline__ void pin_f32x4(f32x4& v) {
    float a = v[0], b = v[1], c = v[2], d = v[3];
    asm volatile("" : "+v"(a), "+v"(b), "+v"(c), "+v"(d));
    v[0] = a; v[1] = b; v[2] = c; v[3] = d;
}

// LDS-only barrier: orders ds ops across the workgroup WITHOUT draining vmcnt.
static __device__ __forceinline__ void barrier_lds_only() {
    asm volatile("s_waitcnt lgkmcnt(0)\n\ts_barrier" ::: "memory");
}

#define MFMA16(A,Bv,C) __builtin_amdgcn_mfma_f32_16x16x32_f16((A),(Bv),(C),0,0,0)

// ---------------------------------------------------------------------------
// Kernel 0: cast x (fp32) -> x16 (f16), one-shot, memory-bound (~15 us).
// ---------------------------------------------------------------------------
__global__ __launch_bounds__(256)
void cvt_x(const float* __restrict__ x, _Float16* __restrict__ x16)
{
    const size_t n4 = (size_t)B_ * T_ * IN_ / 4;
    const size_t stride = (size_t)gridDim.x * 256;
    for (size_t i = (size_t)blockIdx.x * 256 + threadIdx.x; i < n4; i += stride) {
        const float4 v = ((const float4*)x)[i];
        half4 h;
        h[0] = (_Float16)v.x; h[1] = (_Float16)v.y;
        h[2] = (_Float16)v.z; h[3] = (_Float16)v.w;
        ((half4*)x16)[i] = h;
    }
}

// ---------------------------------------------------------------------------
// Kernel 1 (structure H): producer-consumer wave-specialized fused GRU.
// 32 blocks x 1024 thr = 16 waves (4/SIMD). 16 seqs/block (MFMA col = lr).
//   h-waves (w<8):  j-window w. Per step: ds_read xa(t) (xmem) + h(t) (hmem)
//                   -> 12 h-MFMA (C-in seeded with xa / scaled bias)
//                   -> lane-local gates -> h(t+1) to hmem + out store.
//                   ZERO global loads in the loop.
//   x-waves (w>=8): j-window w-8. Per step: 12 x-MFMA for xa(t+1) (bias-
//                   seeded C-in) -> 3 ds_write to xmem[(t+1)&1]; reload
//                   x(t+3) (a full step of latency slack).
// One lgkmcnt-only barrier per step per wave; all buffers double-buffered.
// Gate scales folded into weights: aH/aI rows p=0,1 scaled by -log2e,
// p=2 by -2log2e; gates use raw exp2/rcp (no muls).
// ---------------------------------------------------------------------------
__global__ __launch_bounds__(1024)
void gru_fused(const float* __restrict__ Wih, const float* __restrict__ Whh,
               const float* __restrict__ bih, const float* __restrict__ bhh,
               const _Float16* __restrict__ x16, float* __restrict__ out)
{
    const int tid  = threadIdx.x;
    const int lane = tid & 63;
    const int w    = tid >> 6;        // 0..15
    const int lr   = lane & 15;       // seq col
    const int hi   = lane >> 4;       // 0..3
    const int blk  = blockIdx.x;      // 0..31
    const int g    = blk & 7;
    const int bq   = blk >> 3;
    const int b    = bq * 16 + lr;

    __shared__ _Float16 hmem[2][16 * 128];     // 8 KB, swizzled
    __shared__ f32x4    xmem[2][8][3][64];     // 48 KB: [buf][jw][gate][lane]

    if (w < 8) {
        // ========================= h-wave =========================
        const int jw = w;
        const int jl = jw * 16 + hi * 4;

        half8 aH[3][4];
#pragma unroll
        for (int p = 0; p < 3; ++p)
#pragma unroll
            for (int kt = 0; kt < 4; ++kt) {
                aH[p][kt] = cvt_half8_s(
                    Whh + (size_t)(g * J3_ + p * 128 + jw * 16 + lr) * HG_ + kt * 32 + hi * 8,
                    p == 2 ? S_N : S_RZ);
                pin_frag(aH[p][kt]);
            }
        f32x4 bhn_ = *(const f32x4*)(bhh + g * J3_ + 256 + jl);
        bhn_ = bhn_ * S_N;
        pin_f32x4(bhn_);

        const int gi = (2 * jw + (hi >> 1)) ^ (lr & 7);
        _Float16* hw0 = &hmem[0][lr * 128 + gi * 8 + (hi & 1) * 4];
        _Float16* hw1 = &hmem[1][lr * 128 + gi * 8 + (hi & 1) * 4];
        {
            half4 z; z[0]=(_Float16)0.f; z[1]=(_Float16)0.f; z[2]=(_Float16)0.f; z[3]=(_Float16)0.f;
            *(half4*)hw0 = z;
        }

        f32x4 hreg = (f32x4){0.f, 0.f, 0.f, 0.f};
        float* orow = out + (size_t)b * T_ * IN_ + g * HG_ + jl;
        __syncthreads();

#define H_STEP(PB, HWD)                                                            \
        {                                                                          \
            const f32x4 xa0 = xmem[PB][jw][0][lane];                               \
            const f32x4 xa1 = xmem[PB][jw][1][lane];                               \
            const f32x4 xa2 = xmem[PB][jw][2][lane];                               \
            f32x4 ar = xa0, az = xa1, an = bhn_;                                   \
            _Pragma("unroll")                                                      \
            for (int kt = 0; kt < 4; ++kt) {                                       \
                const half8 bf = *(const half8*)&hmem[PB][lr * 128 + ((4*kt + hi) ^ (lr & 7)) * 8]; \
                ar = MFMA16(aH[0][kt], bf, ar);                                    \
                az = MFMA16(aH[1][kt], bf, az);                                    \
                an = MFMA16(aH[2][kt], bf, an);                                    \
            }                                                                      \
            f32x4 hnew;                                                            \
            _Pragma("unroll")                                                      \
            for (int r = 0; r < 4; ++r) {                                          \
                const float rg = __builtin_amdgcn_rcpf(1.f + __builtin_amdgcn_exp2f(ar[r])); \
                const float zg = __builtin_amdgcn_rcpf(1.f + __builtin_amdgcn_exp2f(az[r])); \
                const float pre = xa2[r] + rg * an[r];                             \
                const float th  = __builtin_fmaf(2.f,                              \
                    __builtin_amdgcn_rcpf(1.f + __builtin_amdgcn_exp2f(pre)), -1.f); \
                hnew[r] = __builtin_fmaf(zg, hreg[r] - th, th);                    \
            }                                                                      \
            hreg = hnew;                                                           \
            half4 hh;                                                              \
            hh[0]=(_Float16)hnew[0]; hh[1]=(_Float16)hnew[1];                      \
            hh[2]=(_Float16)hnew[2]; hh[3]=(_Float16)hnew[3];                      \
            *(half4*)(HWD) = hh;                                                   \
            *(f32x4*)orow = hnew;                                                  \
            barrier_lds_only();                                                    \
            orow += IN_;                                                           \
        }

        for (int t = 0; t < T_; t += 2) {
            H_STEP(0, hw1)
            H_STEP(1, hw0)
        }
#undef H_STEP

    } else {
        // ========================= x-wave =========================
        const int jw = w - 8;
        const int jl = jw * 16 + hi * 4;

        half8 aI[3][4];
#pragma unroll
        for (int p = 0; p < 3; ++p)
#pragma unroll
            for (int kt = 0; kt < 4; ++kt) {
                aI[p][kt] = cvt_half8_s(
                    Wih + (size_t)(g * J3_ + p * 128 + jw * 16 + lr) * HG_ + kt * 32 + hi * 8,
                    p == 2 ? S_N : S_RZ);
                pin_frag(aI[p][kt]);
            }
        f32x4 s0 = (*(const f32x4*)(bih + g * J3_ + jl)
                  + *(const f32x4*)(bhh + g * J3_ + jl)) * S_RZ;
        f32x4 s1 = (*(const f32x4*)(bih + g * J3_ + 128 + jl)
                  + *(const f32x4*)(bhh + g * J3_ + 128 + jl)) * S_RZ;
        f32x4 s2 = (*(const f32x4*)(bih + g * J3_ + 256 + jl)) * S_N;
        pin_f32x4(s0); pin_f32x4(s1); pin_f32x4(s2);

        const _Float16* xrow = x16 + (size_t)b * T_ * IN_ + g * HG_;

        // xa(0) -> xmem[0]
        {
            half8 bx[4];
#pragma unroll
            for (int kt = 0; kt < 4; ++kt)
                bx[kt] = *(const half8*)(xrow + kt * 32 + hi * 8);
            f32x4 a0 = s0, a1 = s1, a2 = s2;
#pragma unroll
            for (int kt = 0; kt < 4; ++kt) {
                a0 = MFMA16(aI[0][kt], bx[kt], a0);
                a1 = MFMA16(aI[1][kt], bx[kt], a1);
                a2 = MFMA16(aI[2][kt], bx[kt], a2);
            }
            xmem[0][jw][0][lane] = a0;
            xmem[0][jw][1][lane] = a1;
            xmem[0][jw][2][lane] = a2;
        }
        half8 bxA[4], bxB[4];
#pragma unroll
        for (int kt = 0; kt < 4; ++kt)
            bxA[kt] = *(const half8*)(xrow + (size_t)1 * IN_ + kt * 32 + hi * 8);
#pragma unroll
        for (int kt = 0; kt < 4; ++kt)
            bxB[kt] = *(const half8*)(xrow + (size_t)2 * IN_ + kt * 32 + hi * 8);
        __syncthreads();

#define X_STEP(PB, BX, TLOAD)                                                      \
        {                                                                          \
            f32x4 a0 = s0, a1 = s1, a2 = s2;                                       \
            _Pragma("unroll")                                                      \
            for (int kt = 0; kt < 4; ++kt) {                                       \
                a0 = MFMA16(aI[0][kt], BX[kt], a0);                                \
                a1 = MFMA16(aI[1][kt], BX[kt], a1);                                \
                a2 = MFMA16(aI[2][kt], BX[kt], a2);                                \
            }                                                                      \
            xmem[PB ^ 1][jw][0][lane] = a0;                                        \
            xmem[PB ^ 1][jw][1][lane] = a1;                                        \
            xmem[PB ^ 1][jw][2][lane] = a2;                                        \
            int tn = (TLOAD); if (tn > T_ - 1) tn = T_ - 1;                        \
            const _Float16* px = xrow + (size_t)tn * IN_;                          \
            _Pragma("unroll")                                                      \
            for (int kt = 0; kt < 4; ++kt)                                         \
                BX[kt] = *(const half8*)(px + kt * 32 + hi * 8);                   \
            barrier_lds_only();                                                    \
        }

        for (int t = 0; t < T_; t += 2) {
            X_STEP(0, bxA, t + 3)
            X_STEP(1, bxB, t + 4)
        }
#undef X_STEP
    }
}

// ---------------------------------------------------------------------------
extern "C" void kernel_launch(void* const* d_in, const int* in_sizes, int n_in,
                              void* d_out, int out_size, void* d_ws, size_t ws_size,
                              hipStream_t stream) {
    (void)in_sizes; (void)n_in; (void)out_size; (void)ws_size;
    const float* x   = (const float*)d_in[0];
    const float* Wih = (const float*)d_in[1];
    const float* Whh = (const float*)d_in[2];
    const float* bih = (const float*)d_in[3];
    const float* bhh = (const float*)d_in[4];
    float* out = (float*)d_out;

    _Float16* x16 = (_Float16*)d_ws;    // 65.5 MB

    cvt_x<<<4096, 256, 0, stream>>>(x, x16);
    gru_fused<<<32, 1024, 0, stream>>>(Wih, Whh, bih, bhh, x16, out);
}

// Round 11
// 430.453 us; speedup vs baseline: 1.3976x; 1.3976x over previous
//
#include <hip/hip_runtime.h>
#include <math.h>

#define B_   64
#define T_   500
#define IN_  1024
#define G_   8
#define HG_  128
#define J3_  384   // 3*HG

typedef _Float16 half8 __attribute__((ext_vector_type(8)));
typedef _Float16 half4 __attribute__((ext_vector_type(4)));
typedef float    f32x4 __attribute__((ext_vector_type(4)));

// sigmoid(a) = rcp(1 + exp2(S_RZ*a)); tanh(p) = 2*rcp(1+exp2(S_N*p))-1.
// Scales folded into the f16 weights and bias seeds (no muls in gates).
#define S_RZ (-1.44269504f)
#define S_N  (-2.88539008f)

static __device__ __forceinline__ half8 cvt_half8_s(const float* p, float s) {
    const float4 a = *(const float4*)p;
    const float4 b = *(const float4*)(p + 4);
    half8 h;
    h[0]=(_Float16)(a.x*s); h[1]=(_Float16)(a.y*s); h[2]=(_Float16)(a.z*s); h[3]=(_Float16)(a.w*s);
    h[4]=(_Float16)(b.x*s); h[5]=(_Float16)(b.y*s); h[6]=(_Float16)(b.z*s); h[7]=(_Float16)(b.w*s);
    return h;
}

// opaque reg-to-reg barrier: prevents rematerialization of loop-invariant state
static __device__ __forceinline__ void pin_frag(half8& h) {
    f32x4 t = __builtin_bit_cast(f32x4, h);
    float a = t[0], b = t[1], c = t[2], d = t[3];
    asm volatile("" : "+v"(a), "+v"(b), "+v"(c), "+v"(d));
    t[0] = a; t[1] = b; t[2] = c; t[3] = d;
    h = __builtin_bit_cast(half8, t);
}
static __device__ __forceinline__ void pin_f32x4(f32x4& v) {
    float a = v[0], b = v[1], c = v[2], d = v[3];
    asm volatile("" : "+v"(a), "+v"(b), "+v"(c), "+v"(d));
    v[0] = a; v[1] = b; v[2] = c; v[3] = d;
}

// LDS-only barrier: orders ds ops across the workgroup WITHOUT draining vmcnt.
static __device__ __forceinline__ void barrier_lds_only() {
    asm volatile("s_waitcnt lgkmcnt(0)\n\ts_barrier" ::: "memory");
}

#define MFMA16(A,Bv,C) __builtin_amdgcn_mfma_f32_16x16x32_f16((A),(Bv),(C),0,0,0)

// ---------------------------------------------------------------------------
// Kernel 0: cast x (fp32) -> x16 (f16), one-shot, memory-bound (~30 us).
// ---------------------------------------------------------------------------
__global__ __launch_bounds__(256)
void cvt_x(const float* __restrict__ x, _Float16* __restrict__ x16)
{
    const size_t n4 = (size_t)B_ * T_ * IN_ / 4;
    const size_t stride = (size_t)gridDim.x * 256;
    for (size_t i = (size_t)blockIdx.x * 256 + threadIdx.x; i < n4; i += stride) {
        const float4 v = ((const float4*)x)[i];
        half4 h;
        h[0] = (_Float16)v.x; h[1] = (_Float16)v.y;
        h[2] = (_Float16)v.z; h[3] = (_Float16)v.w;
        ((half4*)x16)[i] = h;
    }
}

// ---------------------------------------------------------------------------
// Kernel 1 (structure G3 = round-8 chain + column replication for activity):
// 256 blocks x 512 thr (8 waves). Each block runs TWO real sequences,
// replicated across the 16 MFMA columns: b = bp*2 + (lr&1). All columns
// compute (duplicates are free - same chain), only lr<2 lanes store.
// Rationale: PMC cross-check (rounds 8/10) shows the step chain is ~850cy
// and the wall gap is effective clock ~750-800MHz at 32 active CUs.
// 8x more active CUs = same chain, DVFS activity bait.
// Per step: 4 hmem ds_read -> 12 x-MFMA (xa(t+1), bias-seeded C-in)
//           -> BX(t+2) reload -> 12 h-MFMA (2+2 split, xa(t)/bias C-in)
//           -> lane-local folded-scale gates -> swizzled h write
//           -> lgkmcnt-only barrier -> masked out store.
// ---------------------------------------------------------------------------
__global__ __launch_bounds__(512, 1)
void gru_fused(const float* __restrict__ Wih, const float* __restrict__ Whh,
               const float* __restrict__ bih, const float* __restrict__ bhh,
               const _Float16* __restrict__ x16, float* __restrict__ out)
{
    const int tid  = threadIdx.x;
    const int lane = tid & 63;
    const int w    = tid >> 6;        // wave 0..7 == j-tile
    const int lr   = lane & 15;       // MFMA col; real seq = lr&1
    const int hi   = lane >> 4;       // 0..3
    const int blk  = blockIdx.x;      // 0..255
    const int g    = blk & 7;
    const int bp   = blk >> 3;        // 0..31
    const int b    = bp * 2 + (lr & 1);
    const int jl   = w * 16 + hi * 4; // this lane's j base

    __shared__ _Float16 hmem[2][16 * 128];   // 8 KB, swizzled

    // ---- persistent pinned fragments, gate scales folded in ----
    half8 aI[3][4], aH[3][4];
#pragma unroll
    for (int p = 0; p < 3; ++p)
#pragma unroll
        for (int kt = 0; kt < 4; ++kt) {
            const size_t roff = (size_t)(g * J3_ + p * 128 + w * 16 + lr) * HG_
                              + kt * 32 + hi * 8;
            const float s = (p == 2) ? S_N : S_RZ;
            aI[p][kt] = cvt_half8_s(Wih + roff, s);  pin_frag(aI[p][kt]);
            aH[p][kt] = cvt_half8_s(Whh + roff, s);  pin_frag(aH[p][kt]);
        }

    // ---- bias seeds (scaled): r,z fold bih+bhh into x-chain; n splits ----
    const float* bi = bih + g * J3_;
    const float* bh = bhh + g * J3_;
    f32x4 s0 = (*(const f32x4*)(bi + jl)       + *(const f32x4*)(bh + jl))       * S_RZ;
    f32x4 s1 = (*(const f32x4*)(bi + 128 + jl) + *(const f32x4*)(bh + 128 + jl)) * S_RZ;
    f32x4 s2 = (*(const f32x4*)(bi + 256 + jl)) * S_N;
    f32x4 bhn_s = (*(const f32x4*)(bh + 256 + jl)) * S_N;
    pin_f32x4(s0); pin_f32x4(s1); pin_f32x4(s2); pin_f32x4(bhn_s);

    // ---- h = 0 init ----
    f32x4 hreg = (f32x4){0.f, 0.f, 0.f, 0.f};
    {
        const int gi = (2 * w + (hi >> 1)) ^ (lr & 7);
        half4 z; z[0]=(_Float16)0.f; z[1]=(_Float16)0.f; z[2]=(_Float16)0.f; z[3]=(_Float16)0.f;
        *(half4*)&hmem[0][lr * 128 + gi * 8 + (hi & 1) * 4] = z;
    }

    const _Float16* xrow = x16 + (size_t)b * T_ * IN_ + g * HG_;   // + tau*IN_
    float*          orow = out + (size_t)b * T_ * IN_ + g * HG_;   // + tau*IN_

    // ---- prologue: bxB <- x(0), bxA <- x(1); xaA = xa(0) ----
    half8 bxA[4], bxB[4];
#pragma unroll
    for (int kt = 0; kt < 4; ++kt) bxB[kt] = *(const half8*)(xrow + kt * 32 + hi * 8);
#pragma unroll
    for (int kt = 0; kt < 4; ++kt) bxA[kt] = *(const half8*)(xrow + IN_ + kt * 32 + hi * 8);

    f32x4 xaA0 = s0, xaA1 = s1, xaA2 = s2;
#pragma unroll
    for (int kt = 0; kt < 4; ++kt) {
        xaA0 = MFMA16(aI[0][kt], bxB[kt], xaA0);
        xaA1 = MFMA16(aI[1][kt], bxB[kt], xaA1);
        xaA2 = MFMA16(aI[2][kt], bxB[kt], xaA2);
    }
    f32x4 xaB0, xaB1, xaB2;

    __syncthreads();   // once, outside the loop

#define GRU_STEP(TAU, BXc, BXn, xc0, xc1, xc2, xn0, xn1, xn2)                      \
    do {                                                                           \
        const int pb = (TAU) & 1;                                                  \
        /* 1. h B-frags (ds_read issued first; latency hidden under 2&3) */       \
        const half8 bf0 = *(const half8*)&hmem[pb][lr * 128 + (( 0 + hi) ^ (lr & 7)) * 8]; \
        const half8 bf1 = *(const half8*)&hmem[pb][lr * 128 + (( 4 + hi) ^ (lr & 7)) * 8]; \
        const half8 bf2 = *(const half8*)&hmem[pb][lr * 128 + (( 8 + hi) ^ (lr & 7)) * 8]; \
        const half8 bf3 = *(const half8*)&hmem[pb][lr * 128 + ((12 + hi) ^ (lr & 7)) * 8]; \
        /* 2. x-projection for TAU+1 (bias-seeded C-in; h-independent) */          \
        xn0 = s0; xn1 = s1; xn2 = s2;                                              \
        _Pragma("unroll")                                                          \
        for (int kt = 0; kt < 4; ++kt) {                                           \
            xn0 = MFMA16(aI[0][kt], BXc[kt], xn0);                                 \
            xn1 = MFMA16(aI[1][kt], BXc[kt], xn1);                                 \
            xn2 = MFMA16(aI[2][kt], BXc[kt], xn2);                                 \
        }                                                                          \
        /* 3. reload BXn <- x(TAU+2); stays in flight across barriers */           \
        {                                                                          \
            int tn = (TAU) + 2; if (tn > T_ - 1) tn = T_ - 1;                      \
            const _Float16* px = xrow + (size_t)tn * IN_;                          \
            _Pragma("unroll")                                                      \
            for (int kt = 0; kt < 4; ++kt)                                         \
                BXn[kt] = *(const half8*)(px + kt * 32 + hi * 8);                  \
        }                                                                          \
        /* 4. h-MFMA, 2+2 split chains; xa(t)/bias ride C-in (free adds) */        \
        f32x4 h0a = xc0, h1a = xc1, h2a = bhn_s;                                   \
        f32x4 h0b = (f32x4){0.f,0.f,0.f,0.f}, h1b = h0b, h2b = h0b;                \
        h0a = MFMA16(aH[0][0], bf0, h0a);                                          \
        h1a = MFMA16(aH[1][0], bf0, h1a);                                          \
        h2a = MFMA16(aH[2][0], bf0, h2a);                                          \
        h0b = MFMA16(aH[0][2], bf2, h0b);                                          \
        h1b = MFMA16(aH[1][2], bf2, h1b);                                          \
        h2b = MFMA16(aH[2][2], bf2, h2b);                                          \
        h0a = MFMA16(aH[0][1], bf1, h0a);                                          \
        h1a = MFMA16(aH[1][1], bf1, h1a);                                          \
        h2a = MFMA16(aH[2][1], bf1, h2a);                                          \
        h0b = MFMA16(aH[0][3], bf3, h0b);                                          \
        h1b = MFMA16(aH[1][3], bf3, h1b);                                          \
        h2b = MFMA16(aH[2][3], bf3, h2b);                                          \
        const f32x4 ar = h0a + h0b;   /* = S_RZ*(xr+hr+biases) */                  \
        const f32x4 az = h1a + h1b;                                                \
        const f32x4 an = h2a + h2b;   /* = S_N*(hn+bhn) */                         \
        /* 5. lane-local gates, folded scales (6 trans + 7 VALU per j) */          \
        f32x4 hnew;                                                                \
        _Pragma("unroll")                                                          \
        for (int r = 0; r < 4; ++r) {                                              \
            const float rg = __builtin_amdgcn_rcpf(1.f + __builtin_amdgcn_exp2f(ar[r])); \
            const float zg = __builtin_amdgcn_rcpf(1.f + __builtin_amdgcn_exp2f(az[r])); \
            const float pre = xc2[r] + rg * an[r];      /* = S_N*(xn + rg*hn) */   \
            const float th  = __builtin_fmaf(2.f,                                  \
                __builtin_amdgcn_rcpf(1.f + __builtin_amdgcn_exp2f(pre)), -1.f);   \
            hnew[r] = __builtin_fmaf(zg, hreg[r] - th, th);                        \
        }                                                                          \
        hreg = hnew;                                                               \
        /* 6. write h for next step (swizzled), lds-only barrier */                \
        {                                                                          \
            half4 hh;                                                              \
            hh[0]=(_Float16)hnew[0]; hh[1]=(_Float16)hnew[1];                      \
            hh[2]=(_Float16)hnew[2]; hh[3]=(_Float16)hnew[3];                      \
            const int gi = (2 * w + (hi >> 1)) ^ (lr & 7);                         \
            *(half4*)&hmem[pb ^ 1][lr * 128 + gi * 8 + (hi & 1) * 4] = hh;         \
        }                                                                          \
        barrier_lds_only();                                                        \
        /* 7. masked out store (cols >=2 are duplicates) */                        \
        if (lr < 2) *(f32x4*)(orow + (size_t)(TAU) * IN_ + jl) = hnew;             \
    } while (0)

    for (int t = 0; t < T_; t += 2) {
        GRU_STEP(t,     bxA, bxB, xaA0, xaA1, xaA2, xaB0, xaB1, xaB2);
        GRU_STEP(t + 1, bxB, bxA, xaB0, xaB1, xaB2, xaA0, xaA1, xaA2);
    }
#undef GRU_STEP
}

// ---------------------------------------------------------------------------
extern "C" void kernel_launch(void* const* d_in, const int* in_sizes, int n_in,
                              void* d_out, int out_size, void* d_ws, size_t ws_size,
                              hipStream_t stream) {
    (void)in_sizes; (void)n_in; (void)out_size; (void)ws_size;
    const float* x   = (const float*)d_in[0];
    const float* Wih = (const float*)d_in[1];
    const float* Whh = (const float*)d_in[2];
    const float* bih = (const float*)d_in[3];
    const float* bhh = (const float*)d_in[4];
    float* out = (float*)d_out;

    _Float16* x16 = (_Float16*)d_ws;    // 65.5 MB

    cvt_x<<<4096, 256, 0, stream>>>(x, x16);
    gru_fused<<<256, 512, 0, stream>>>(Wih, Whh, bih, bhh, x16, out);
}